// Round 8
// baseline (689.643 us; speedup 1.0000x reference)
//
#include <hip/hip_runtime.h>

#define Bn 2
#define Cn 256
#define Hn 128
#define Wn 128
#define HWn 16384
#define NCn 80

typedef __attribute__((ext_vector_type(4))) float f32x4;
typedef __attribute__((ext_vector_type(8))) short bf16x8;

__device__ __forceinline__ float blo(unsigned u) {
    union { unsigned u; float f; } x; x.u = u << 16; return x.f;
}
__device__ __forceinline__ float braw(unsigned u) {   // high bf16 + mantissa garbage (<=1ulp)
    union { unsigned u; float f; } x; x.u = u; return x.f;
}
__device__ __forceinline__ unsigned short f2bf(float f) {
    union { float f; unsigned u; } x; x.f = f;
    unsigned u = x.u + 0x7fffu + ((x.u >> 16) & 1u);   // RNE
    return (unsigned short)(u >> 16);
}
__device__ __forceinline__ unsigned pk2bf(float e0, float e1) {
    unsigned r;
    asm("v_cvt_pk_bf16_f32 %0, %1, %2" : "=v"(r) : "v"(e0), "v"(e1));
    return r;
}

// async global->LDS, 16B per lane, wave-uniform LDS base + lane*16
#define GLOAD16(gp, lp) __builtin_amdgcn_global_load_lds( \
    (__attribute__((address_space(1))) unsigned int*)(gp), \
    (__attribute__((address_space(3))) unsigned int*)(lp), 16, 0, 0)

// ---------- x (NCHW f32) -> NHWC bf16 ----------
__global__ __launch_bounds__(256) void xinK(const float* __restrict__ x,
                                            unsigned short* __restrict__ o) {
    __shared__ float tb[32][33];
    const int b = blockIdx.z;
    const int hw0 = blockIdx.x * 32, c0 = blockIdx.y * 32;
    const int tx = threadIdx.x & 31, ty = threadIdx.x >> 5;
    const float* ip = x + ((size_t)(b * Cn + c0)) * HWn + hw0;
#pragma unroll
    for (int r = 0; r < 4; ++r) tb[ty + 8 * r][tx] = ip[(size_t)(ty + 8 * r) * HWn + tx];
    __syncthreads();
    unsigned short* op = o + ((size_t)(b * HWn + hw0)) * Cn + c0;
#pragma unroll
    for (int r = 0; r < 4; ++r) op[(size_t)(ty + 8 * r) * Cn + tx] = f2bf(tb[tx][ty + 8 * r]);
}

// ---------- fused weight repack (coalesced) + ZB zero ----------
struct WPtrs { const float* p[9]; };
__global__ __launch_bounds__(256) void repackAll(WPtrs wsrc, unsigned short* __restrict__ dst,
                                                 unsigned short* __restrict__ zb) {
    if (blockIdx.x == 0) { zb[threadIdx.x] = 0; zb[256 + threadIdx.x] = 0; }
    const int t = blockIdx.x * 256 + threadIdx.x;     // < 589824
    const int widx = t >> 16;                          // 0..8
    const int r = t & 65535;                           // oc*256+ic
    const float* s = wsrc.p[widx] + (size_t)r * 9;
    float v[9];
#pragma unroll
    for (int k = 0; k < 9; ++k) v[k] = s[k];
    unsigned short* d = dst + (size_t)widx * 589824 + r;
#pragma unroll
    for (int k = 0; k < 9; ++k) d[(size_t)k * 65536] = f2bf(v[k]);
}

// ---------- fused head repack ----------
struct HPtrs { const float* w[3]; };
__global__ __launch_bounds__(256) void repackHeads(HPtrs hs, unsigned short* __restrict__ dst) {
    const int t = blockIdx.x * 256 + threadIdx.x;     // < 160*256
    const int ic = t & 255, row = t >> 8;
    int which, oc, OC;
    if (row < 32)       { which = 0; oc = row;       OC = 27; }
    else if (row < 128) { which = 1; oc = row - 32;  OC = 80; }
    else                { which = 2; oc = row - 128; OC = 18; }
    dst[t] = (oc < OC) ? f2bf(hs.w[which][(size_t)oc * Cn + ic]) : (unsigned short)0;
}

struct CJobs {
    const unsigned short* feat[2];
    const unsigned short* W[2];
    const float* bias[2];
    unsigned short* out[2];
};

// ---------- 256x256 implicit-GEMM 3x3 conv (dual-job), 2-phase (proven r5) ----------
// grid (128, 1, NJ), block 512 (8 waves, 2 oc x 4 px), tile 256oc x 256px, BK=64
__global__ __launch_bounds__(512, 2) void convGemm256(CJobs jobs,
                                                      const unsigned short* __restrict__ zb) {
    const int jz = blockIdx.z;
    const unsigned short* feat = jobs.feat[jz];
    const unsigned short* Wp = jobs.W[jz];
    const float* bias = jobs.bias[jz];
    unsigned short* outp = jobs.out[jz];

    __shared__ __align__(16) unsigned short lA[2][16384];   // 256oc x 64ch
    __shared__ __align__(16) unsigned short lB[2][16384];   // 256px x 64ch
    const int tid = threadIdx.x;
    const int l = tid & 63, w = tid >> 6;
    const int w_oc = w & 1, w_px = w >> 1;        // 2 x 4
    const int g = (blockIdx.x & 7) * 16 + (blockIdx.x >> 3);   // XCD-chunked, 128 tiles
    const int ry0 = g * 2;                         // first of 2 image rows
    const int b = ry0 >> 7, y0 = ry0 & 127;
    const int lr = l & 15, lg = l >> 4;

    int rI[4], cI[4], dI[4];
#pragma unroll
    for (int i = 0; i < 4; ++i) {
        int ps = (i * 8 + w) * 64 + l;            // 2048 slots = 256 rows x 8 chunks
        rI[i] = ps >> 3;
        cI[i] = ((ps & 7) ^ (rI[i] & 7)) * 8;     // pre-swizzled source chunk
        dI[i] = (i * 8 + w) * 512;                // wave-uniform LDS elem base
    }

    f32x4 acc[8][4];
#pragma unroll
    for (int i = 0; i < 8; ++i)
#pragma unroll
        for (int j = 0; j < 4; ++j) acc[i][j] = (f32x4){0.f, 0.f, 0.f, 0.f};

    auto stage = [&](int p, int bufIdx) {
        const int k = p >> 2, c0 = (p & 3) * 64;
        const int dy = k / 3 - 1, dx = k % 3 - 1;
        const unsigned short* wk = Wp + (size_t)k * 65536 + c0;
        unsigned short* la = lA[bufIdx];
        unsigned short* lb = lB[bufIdx];
#pragma unroll
        for (int i = 0; i < 4; ++i)
            GLOAD16(wk + rI[i] * Cn + cI[i], la + dI[i]);
#pragma unroll
        for (int i = 0; i < 4; ++i) {
            const int s = rI[i];
            const int yy = y0 + (s >> 7) + dy;
            const int xx = (s & 127) + dx;
            const bool v = ((unsigned)yy < (unsigned)Hn) && ((unsigned)xx < (unsigned)Wn);
            const unsigned short* gp = v
                ? feat + (((size_t)(b * Hn + yy)) * Wn + xx) * Cn + c0 + cI[i]
                : zb;
            GLOAD16(gp, lb + dI[i]);
        }
    };

    stage(0, 0);
    __syncthreads();

#pragma unroll 1
    for (int p = 0; p < 36; ++p) {
        const int cur = p & 1;
        if (p < 35) stage(p + 1, cur ^ 1);      // async, overlaps MFMA below
        const unsigned short* la = lA[cur];
        const unsigned short* lb = lB[cur];
#pragma unroll
        for (int h = 0; h < 2; ++h) {
            const int ch = h * 4 + lg;
            bf16x8 av[8], bv[4];
#pragma unroll
            for (int fm = 0; fm < 8; ++fm) {
                const int row = w_oc * 128 + fm * 16 + lr;
                av[fm] = *(const bf16x8*)&la[row * 64 + ((ch ^ (row & 7)) * 8)];
            }
#pragma unroll
            for (int fn = 0; fn < 4; ++fn) {
                const int row = w_px * 64 + fn * 16 + lr;
                bv[fn] = *(const bf16x8*)&lb[row * 64 + ((ch ^ (row & 7)) * 8)];
            }
#pragma unroll
            for (int fm = 0; fm < 8; ++fm)
#pragma unroll
                for (int fn = 0; fn < 4; ++fn)
                    acc[fm][fn] = __builtin_amdgcn_mfma_f32_16x16x32_bf16(
                        av[fm], bv[fn], acc[fm][fn], 0, 0, 0);
        }
        __syncthreads();
    }

#pragma unroll
    for (int fm = 0; fm < 8; ++fm) {
        const int oc = w_oc * 128 + fm * 16 + lg * 4;
        const float b0 = bias[oc], b1 = bias[oc + 1], b2 = bias[oc + 2], b3 = bias[oc + 3];
#pragma unroll
        for (int fn = 0; fn < 4; ++fn) {
            const int px = w_px * 64 + fn * 16 + lr;     // 0..255
            f32x4 v = acc[fm][fn];
            uint2 st;
            st.x = pk2bf(fmaxf(v[0] + b0, 0.f), fmaxf(v[1] + b1, 0.f));
            st.y = pk2bf(fmaxf(v[2] + b2, 0.f), fmaxf(v[3] + b3, 0.f));
            *(uint2*)&outp[(((size_t)(ry0 + (px >> 7))) * Wn + (px & 127)) * Cn + oc] = st;
        }
    }
}

// ---------- 128^2 implicit-GEMM 3x3 conv (single job, for init conv) ----------
__global__ __launch_bounds__(256, 2) void convGemm(const unsigned short* __restrict__ feat,
                                                   const unsigned short* __restrict__ Wp,
                                                   const float* __restrict__ bias,
                                                   const unsigned short* __restrict__ zb,
                                                   unsigned short* __restrict__ out) {
    __shared__ __align__(16) unsigned short lA[2][8192];
    __shared__ __align__(16) unsigned short lB[2][8192];
    const int tid = threadIdx.x;
    const int l = tid & 63, w = tid >> 6;
    const int w_oc = w & 1, w_px = w >> 1;
    const int ry = (blockIdx.x & 7) * 32 + (blockIdx.x >> 3);
    const int b = ry >> 7, y = ry & 127;
    const int oc0 = blockIdx.y * 128;
    const int lr = l & 15, lg = l >> 4;

    int rI[4], cI[4], dI[4];
#pragma unroll
    for (int i = 0; i < 4; ++i) {
        int ps = (i * 4 + w) * 64 + l;
        rI[i] = ps >> 3;
        cI[i] = ((ps & 7) ^ (rI[i] & 7)) * 8;
        dI[i] = (i * 4 + w) * 512;
    }

    f32x4 acc[4][4];
#pragma unroll
    for (int i = 0; i < 4; ++i)
#pragma unroll
        for (int j = 0; j < 4; ++j) acc[i][j] = (f32x4){0.f, 0.f, 0.f, 0.f};

    auto stage = [&](int p, int bufIdx) {
        const int k = p >> 2, c0 = (p & 3) * 64;
        const int dy = k / 3 - 1, dx = k % 3 - 1;
        const int yy = y + dy;
        const bool vy = (unsigned)yy < (unsigned)Hn;
        const size_t fbase = ((size_t)(b * Hn + yy)) * Wn;
        const unsigned short* wk = Wp + (size_t)k * 65536 + (size_t)oc0 * Cn + c0;
        unsigned short* la = lA[bufIdx];
        unsigned short* lb = lB[bufIdx];
#pragma unroll
        for (int i = 0; i < 4; ++i)
            GLOAD16(wk + rI[i] * Cn + cI[i], la + dI[i]);
#pragma unroll
        for (int i = 0; i < 4; ++i) {
            const int pxs = rI[i] + dx;
            const unsigned short* g = (vy && (unsigned)pxs < (unsigned)Wn)
                ? feat + ((fbase + pxs) * Cn + c0 + cI[i])
                : zb;
            GLOAD16(g, lb + dI[i]);
        }
    };

    stage(0, 0);
    __syncthreads();

#pragma unroll 1
    for (int p = 0; p < 36; ++p) {
        const int cur = p & 1;
        if (p < 35) stage(p + 1, cur ^ 1);
        const unsigned short* la = lA[cur];
        const unsigned short* lb = lB[cur];
#pragma unroll
        for (int h = 0; h < 2; ++h) {
            const int ch = h * 4 + lg;
            bf16x8 av[4], bv[4];
#pragma unroll
            for (int fm = 0; fm < 4; ++fm) {
                const int row = w_oc * 64 + fm * 16 + lr;
                av[fm] = *(const bf16x8*)&la[row * 64 + ((ch ^ (row & 7)) * 8)];
            }
#pragma unroll
            for (int fn = 0; fn < 4; ++fn) {
                const int row = w_px * 64 + fn * 16 + lr;
                bv[fn] = *(const bf16x8*)&lb[row * 64 + ((ch ^ (row & 7)) * 8)];
            }
#pragma unroll
            for (int fm = 0; fm < 4; ++fm)
#pragma unroll
                for (int fn = 0; fn < 4; ++fn)
                    acc[fm][fn] = __builtin_amdgcn_mfma_f32_16x16x32_bf16(
                        av[fm], bv[fn], acc[fm][fn], 0, 0, 0);
        }
        __syncthreads();
    }

#pragma unroll
    for (int fm = 0; fm < 4; ++fm) {
        const int ocb = oc0 + w_oc * 64 + fm * 16 + lg * 4;
        const float b0 = bias[ocb], b1 = bias[ocb + 1], b2 = bias[ocb + 2], b3 = bias[ocb + 3];
#pragma unroll
        for (int fn = 0; fn < 4; ++fn) {
            const int px = w_px * 64 + fn * 16 + lr;
            f32x4 v = acc[fm][fn];
            uint2 st;
            st.x = pk2bf(fmaxf(v[0] + b0, 0.f), fmaxf(v[1] + b1, 0.f));
            st.y = pk2bf(fmaxf(v[2] + b2, 0.f), fmaxf(v[3] + b3, 0.f));
            *(uint2*)&out[((size_t)ry * Wn + px) * Cn + ocb] = st;
        }
    }
}

// ---------- deformable conv: 256oc x 64px sampled implicit GEMM, dual-job fused ----------
// grid (1024), block 512 (8 waves, 4 oc x 2 px), BK=64, (fm,fn)=(4,2), 80 KB LDS.
// Statically-unrolled 4-phase k-group: corners prefetched one FULL phase ahead
// (two alternating reg sets), offsets for k+1 prefetched one phase ahead; interp
// packing via v_cvt_pk_bf16_f32; hi-half unpack without AND.
struct DJobs {
    const unsigned short* feat[2];
    const unsigned short* W[2];
    unsigned short* out[2];
    int mask[2];
};
__global__ __launch_bounds__(512, 4) void dcnGemm(DJobs jobs,
                                                  const float* __restrict__ o27) {
    const int jz = blockIdx.x >> 9;
    const unsigned short* feat = jobs.feat[jz];
    const unsigned short* Wp = jobs.W[jz];
    unsigned short* outp = jobs.out[jz];
    const bool HASMASK = jobs.mask[jz] != 0;

    __shared__ __align__(16) unsigned short lA[2][16384];   // 256oc x 64ch
    __shared__ __align__(16) unsigned short lB[2][4096];    // 64px x 64ch
    const int tid = threadIdx.x;
    const int l = tid & 63, w = tid >> 6;
    const int w_oc = w & 3, w_px = w >> 2;
    const int lb_ = blockIdx.x & 511;
    const int g = (lb_ & 7) * 64 + (lb_ >> 3);  // XCD-chunked
    const int ry = g >> 1, st = g & 1;
    const int b = ry >> 7, y = ry & 127;
    const int x0 = st * 64;
    const int lr = l & 15, lg = l >> 4;

    int rIA[4], cIA[4], dIA[4];
#pragma unroll
    for (int i = 0; i < 4; ++i) {
        int ps = (i * 8 + w) * 64 + l;
        rIA[i] = ps >> 3;
        cIA[i] = ((ps & 7) ^ (rIA[i] & 7)) * 8;
        dIA[i] = (i * 8 + w) * 512;
    }

    const int sp = tid >> 3;          // sampled px 0..63
    const int pc = tid & 7;           // chunk 0..7
    const int xg = x0 + sp;
    const int wslot = sp * 64 + ((pc ^ (sp & 7)) * 8);

    const float* ob = o27 + (size_t)b * 27 * HWn + y * Wn + xg;
    const unsigned short* fb = feat + (size_t)b * HWn * Cn;

    f32x4 acc[4][2];
#pragma unroll
    for (int i = 0; i < 4; ++i)
#pragma unroll
        for (int j = 0; j < 2; ++j) acc[i][j] = (f32x4){0.f, 0.f, 0.f, 0.f};

    // cur/nxt sampling params
    int ci0, ci1, ci2, ci3;        float cw0, cw1, cw2, cw3;
    int ni0, ni1, ni2, ni3;        float nw0, nw1, nw2, nw3;
    float pofy, pofx, pom;         // offset prefetch regs

    auto sampCompute = [&](int k, float offy, float offx, float m,
                           int& o0, int& o1, int& o2, int& o3,
                           float& u0, float& u1, float& u2, float& u3) {
        const float py = (float)(y + k / 3 - 1) + offy;
        const float px = (float)(xg + k % 3 - 1) + offx;
        const float y0f = floorf(py), x0f = floorf(px);
        const float wy1 = py - y0f, wx1 = px - x0f;
        const int iy0 = (int)y0f, ix0 = (int)x0f;
        const int iy1 = iy0 + 1, ix1 = ix0 + 1;
        const bool vy0 = (unsigned)iy0 < (unsigned)Hn, vy1 = (unsigned)iy1 < (unsigned)Hn;
        const bool vx0 = (unsigned)ix0 < (unsigned)Wn, vx1 = (unsigned)ix1 < (unsigned)Wn;
        const int yc0 = min(max(iy0, 0), Hn - 1), yc1 = min(max(iy1, 0), Hn - 1);
        const int xc0 = min(max(ix0, 0), Wn - 1), xc1 = min(max(ix1, 0), Wn - 1);
        u0 = (vy0 && vx0) ? (1.f - wy1) * (1.f - wx1) * m : 0.f;
        u1 = (vy0 && vx1) ? (1.f - wy1) * wx1 * m : 0.f;
        u2 = (vy1 && vx0) ? wy1 * (1.f - wx1) * m : 0.f;
        u3 = (vy1 && vx1) ? wy1 * wx1 * m : 0.f;
        o0 = (yc0 * Wn + xc0) * Cn;
        o1 = (yc0 * Wn + xc1) * Cn;
        o2 = (yc1 * Wn + xc0) * Cn;
        o3 = (yc1 * Wn + xc1) * Cn;
    };

    int4 qa0, qa1, qa2, qa3;   // set A
    int4 qb0, qb1, qb2, qb3;   // set B

#define DFILL(Q0, Q1, Q2, Q3, I0, I1, I2, I3, CBI) do { \
        const int cb_ = (CBI) * 64 + pc * 8; \
        Q0 = *(const int4*)(fb + (I0) + cb_); \
        Q1 = *(const int4*)(fb + (I1) + cb_); \
        Q2 = *(const int4*)(fb + (I2) + cb_); \
        Q3 = *(const int4*)(fb + (I3) + cb_); \
    } while (0)

#define DWRITE(Q0, Q1, Q2, Q3, U0, U1, U2, U3, BUF) do { \
        unsigned uu[4]; \
        _Pragma("unroll") for (int jj = 0; jj < 4; ++jj) { \
            const unsigned a0 = ((const unsigned*)&Q0)[jj]; \
            const unsigned a1 = ((const unsigned*)&Q1)[jj]; \
            const unsigned a2 = ((const unsigned*)&Q2)[jj]; \
            const unsigned a3 = ((const unsigned*)&Q3)[jj]; \
            float e0 = U0 * blo(a0) + U1 * blo(a1) + U2 * blo(a2) + U3 * blo(a3); \
            float e1 = U0 * braw(a0) + U1 * braw(a1) + U2 * braw(a2) + U3 * braw(a3); \
            uu[jj] = pk2bf(e0, e1); \
        } \
        int4 pk_; pk_.x = uu[0]; pk_.y = uu[1]; pk_.z = uu[2]; pk_.w = uu[3]; \
        *(int4*)&lB[BUF][wslot] = pk_; \
    } while (0)

    auto stageA = [&](int p) {
        const int k = p >> 2, c0 = (p & 3) * 64, bf = p & 1;
        const unsigned short* wk = Wp + (size_t)k * 65536 + c0;
        unsigned short* la = lA[bf];
#pragma unroll
        for (int i = 0; i < 4; ++i)
            GLOAD16(wk + rIA[i] * Cn + cIA[i], la + dIA[i]);
    };

#define DMFMA(BUF) do { \
        const unsigned short* la_ = lA[BUF]; \
        const unsigned short* lb2_ = lB[BUF]; \
        _Pragma("unroll") for (int h = 0; h < 2; ++h) { \
            const int ch = h * 4 + lg; \
            bf16x8 av[4], bv[2]; \
            _Pragma("unroll") for (int fm = 0; fm < 4; ++fm) { \
                const int row = w_oc * 64 + fm * 16 + lr; \
                av[fm] = *(const bf16x8*)&la_[row * 64 + ((ch ^ (row & 7)) * 8)]; } \
            _Pragma("unroll") for (int fn = 0; fn < 2; ++fn) { \
                const int row = w_px * 32 + fn * 16 + lr; \
                bv[fn] = *(const bf16x8*)&lb2_[row * 64 + ((ch ^ (row & 7)) * 8)]; } \
            _Pragma("unroll") for (int fm = 0; fm < 4; ++fm) \
                _Pragma("unroll") for (int fn = 0; fn < 2; ++fn) \
                    acc[fm][fn] = __builtin_amdgcn_mfma_f32_16x16x32_bf16( \
                        av[fm], bv[fn], acc[fm][fn], 0, 0, 0); \
        } \
    } while (0)

    // ---- prologue (k=0) ----
    {
        const float offy = ob[0];
        const float offx = ob[(size_t)HWn];
        const float m = HASMASK ? ob[(size_t)18 * HWn] : 1.f;
        sampCompute(0, offy, offx, m, ci0, ci1, ci2, ci3, cw0, cw1, cw2, cw3);
    }
    DFILL(qa0, qa1, qa2, qa3, ci0, ci1, ci2, ci3, 0);   // corners for p=0
    stageA(0);
    DWRITE(qa0, qa1, qa2, qa3, cw0, cw1, cw2, cw3, 0);  // lB[0] for p=0
    DFILL(qb0, qb1, qb2, qb3, ci0, ci1, ci2, ci3, 1);   // corners for p=1
    __syncthreads();

#pragma unroll 1
    for (int kk = 0; kk < 9; ++kk) {
        const bool moreK = (kk < 8);
        // ---- CC=0 (p=4kk, buf0): consume qB(write p+1), fill qA(for p+2) ----
        if (moreK) {
            const int kn = kk + 1;
            pofy = ob[(size_t)(2 * kn) * HWn];
            pofx = ob[(size_t)(2 * kn + 1) * HWn];
            pom = HASMASK ? ob[(size_t)(18 + kn) * HWn] : 1.f;
        }
        stageA(4 * kk + 1);
        DFILL(qa0, qa1, qa2, qa3, ci0, ci1, ci2, ci3, 2);
        DMFMA(0);
        DWRITE(qb0, qb1, qb2, qb3, cw0, cw1, cw2, cw3, 1);
        __syncthreads();
        // ---- CC=1 (p=4kk+1, buf1): consume qA, fill qB ----
        if (moreK)
            sampCompute(kk + 1, pofy, pofx, pom, ni0, ni1, ni2, ni3, nw0, nw1, nw2, nw3);
        stageA(4 * kk + 2);
        DFILL(qb0, qb1, qb2, qb3, ci0, ci1, ci2, ci3, 3);
        DMFMA(1);
        DWRITE(qa0, qa1, qa2, qa3, cw0, cw1, cw2, cw3, 0);
        __syncthreads();
        // ---- CC=2 (p=4kk+2, buf0): consume qB, fill qA (next k) ----
        stageA(4 * kk + 3);
        if (moreK) DFILL(qa0, qa1, qa2, qa3, ni0, ni1, ni2, ni3, 0);
        DMFMA(0);
        DWRITE(qb0, qb1, qb2, qb3, cw0, cw1, cw2, cw3, 1);
        __syncthreads();
        // ---- CC=3 (p=4kk+3, buf1): consume qA (next-k cw), fill qB (next k) ----
        if (moreK) {
            stageA(4 * kk + 4);
            DFILL(qb0, qb1, qb2, qb3, ni0, ni1, ni2, ni3, 1);
        }
        DMFMA(1);
        if (moreK) {
            DWRITE(qa0, qa1, qa2, qa3, nw0, nw1, nw2, nw3, 0);
            ci0 = ni0; ci1 = ni1; ci2 = ni2; ci3 = ni3;
            cw0 = nw0; cw1 = nw1; cw2 = nw2; cw3 = nw3;
        }
        __syncthreads();
    }

#pragma unroll
    for (int fm = 0; fm < 4; ++fm) {
        const int oc = w_oc * 64 + fm * 16 + lg * 4;
#pragma unroll
        for (int fn = 0; fn < 2; ++fn) {
            const int px = x0 + w_px * 32 + fn * 16 + lr;
            f32x4 v = acc[fm][fn];
            uint2 stv;
            stv.x = pk2bf(fmaxf(v[0], 0.f), fmaxf(v[1], 0.f));
            stv.y = pk2bf(fmaxf(v[2], 0.f), fmaxf(v[3], 0.f));
            *(uint2*)&outp[((size_t)ry * Wn + px) * Cn + oc] = stv;
        }
    }
#undef DFILL
#undef DWRITE
#undef DMFMA
}

// ---------- MFMA 1x1 head ----------
template <int OC, int PM, bool ADD, bool POST>
__global__ __launch_bounds__(256, 2) void headGemm(const unsigned short* __restrict__ feat,
                                                   const unsigned short* __restrict__ Wp,
                                                   const float* __restrict__ bias,
                                                   float* __restrict__ out,
                                                   const float* __restrict__ add,
                                                   int addC,
                                                   float* __restrict__ reg) {
    constexpr int MF = PM / 16;
    constexpr int NA = PM * 8 / 256;
    __shared__ __align__(16) unsigned short lA[PM * 64];
    __shared__ __align__(16) unsigned short lB[128 * 64];
    __shared__ float lR[POST ? 18 : 1][POST ? 128 : 1];
    const int tid = threadIdx.x;
    const int l = tid & 63, w = tid >> 6;
    const int ry = (blockIdx.x & 7) * 32 + (blockIdx.x >> 3);
    const int b = ry >> 7, y = ry & 127;
    const int lr = l & 15, lg = l >> 4;

    int rIA[NA], cIA[NA], dIA[NA];
#pragma unroll
    for (int i = 0; i < NA; ++i) {
        int ps = (i * 4 + w) * 64 + l;
        rIA[i] = ps >> 3;
        cIA[i] = ((ps & 7) ^ (rIA[i] & 7)) * 8;
        dIA[i] = (i * 4 + w) * 512;
    }
    int rIB[4], cIB[4], dIB[4];
#pragma unroll
    for (int i = 0; i < 4; ++i) {
        int ps = (i * 4 + w) * 64 + l;
        rIB[i] = ps >> 3;
        cIB[i] = ((ps & 7) ^ (rIB[i] & 7)) * 8;
        dIB[i] = (i * 4 + w) * 512;
    }

    f32x4 acc[MF][2];
#pragma unroll
    for (int i = 0; i < MF; ++i)
#pragma unroll
        for (int j = 0; j < 2; ++j) acc[i][j] = (f32x4){0.f, 0.f, 0.f, 0.f};

    const unsigned short* frow = feat + ((size_t)ry * Wn) * Cn;

#pragma unroll 1
    for (int cc = 0; cc < 4; ++cc) {
        const int c0 = cc * 64;
#pragma unroll
        for (int i = 0; i < NA; ++i)
            GLOAD16(Wp + (size_t)rIA[i] * Cn + c0 + cIA[i], &lA[dIA[i]]);
#pragma unroll
        for (int i = 0; i < 4; ++i)
            GLOAD16(frow + (size_t)rIB[i] * Cn + c0 + cIB[i], &lB[dIB[i]]);
        __syncthreads();
#pragma unroll
        for (int h = 0; h < 2; ++h) {
            const int ch = h * 4 + lg;
            bf16x8 av[MF], bv[2];
#pragma unroll
            for (int fm = 0; fm < MF; ++fm) {
                const int row = fm * 16 + lr;
                av[fm] = *(const bf16x8*)&lA[row * 64 + ((ch ^ (row & 7)) * 8)];
            }
#pragma unroll
            for (int fn = 0; fn < 2; ++fn) {
                const int row = w * 32 + fn * 16 + lr;
                bv[fn] = *(const bf16x8*)&lB[row * 64 + ((ch ^ (row & 7)) * 8)];
            }
#pragma unroll
            for (int fm = 0; fm < MF; ++fm)
#pragma unroll
                for (int fn = 0; fn < 2; ++fn)
                    acc[fm][fn] = __builtin_amdgcn_mfma_f32_16x16x32_bf16(
                        av[fm], bv[fn], acc[fm][fn], 0, 0, 0);
        }
        __syncthreads();
    }

    if (!POST) {
#pragma unroll
        for (int fm = 0; fm < MF; ++fm) {
            const int ocb = fm * 16 + lg * 4;
            if (ocb >= OC) break;
#pragma unroll
            for (int j = 0; j < 4; ++j) {
                const int oc = ocb + j;
                if (oc >= OC) break;
                const float bs = bias[oc];
#pragma unroll
                for (int fn = 0; fn < 2; ++fn) {
                    const int px = w * 32 + fn * 16 + lr;
                    float r = acc[fm][fn][j] + bs;
                    if (ADD) r += add[((size_t)(b * addC + oc)) * HWn + y * Wn + px];
                    out[((size_t)(b * OC + oc)) * HWn + y * Wn + px] = r;
                }
            }
        }
    } else {
#pragma unroll
        for (int fm = 0; fm < MF; ++fm) {
            const int ocb = fm * 16 + lg * 4;
#pragma unroll
            for (int j = 0; j < 4; ++j) {
                const int oc = ocb + j;
                if (oc < 18) {
                    const float bs = bias[oc];
#pragma unroll
                    for (int fn = 0; fn < 2; ++fn) {
                        const int px = w * 32 + fn * 16 + lr;
                        float r = acc[fm][fn][j] + bs
                                + add[((size_t)(b * addC + oc)) * HWn + y * Wn + px];
                        lR[oc][px] = r;
                    }
                }
            }
        }
        __syncthreads();
        if (tid < 128) {
            const int px = tid;
            float v[18];
#pragma unroll
            for (int c = 0; c < 18; ++c) v[c] = lR[c][px];
            float s0 = 0.f, s1 = 0.f;
#pragma unroll
            for (int q = 0; q < 9; ++q) { s0 += v[2 * q]; s1 += v[2 * q + 1]; }
            float m0 = s0 * (1.f / 9.f), m1 = s1 * (1.f / 9.f);
            float w0 = 0.f, w1 = 0.f;
#pragma unroll
            for (int q = 0; q < 9; ++q) {
                w0 = fmaxf(w0, fabsf(v[2 * q] + m0));
                w1 = fmaxf(w1, fabsf(v[2 * q + 1] + m1));
            }
            const size_t hw = (size_t)y * Wn + px;
            out[(size_t)(b * 2 + 0) * HWn + hw] = w0;
            out[(size_t)(b * 2 + 1) * HWn + hw] = w1;
            reg[(size_t)(b * 2 + 0) * HWn + hw] = m0;
            reg[(size_t)(b * 2 + 1) * HWn + hw] = m1;
        }
    }
}

// ---------- host ----------
extern "C" void kernel_launch(void* const* d_in, const int* in_sizes, int n_in,
                              void* d_out, int out_size, void* d_ws, size_t ws_size,
                              hipStream_t stream) {
    const float* x           = (const float*)d_in[0];
    const float* cls_w0      = (const float*)d_in[1];
    const float* cls_b0      = (const float*)d_in[2];
    const float* reg_w0      = (const float*)d_in[3];
    const float* reg_b0      = (const float*)d_in[4];
    const float* cls_w1      = (const float*)d_in[5];
    const float* cls_b1      = (const float*)d_in[6];
    const float* reg_w1      = (const float*)d_in[7];
    const float* reg_b1      = (const float*)d_in[8];
    const float* cls_w2      = (const float*)d_in[9];
    const float* cls_b2      = (const float*)d_in[10];
    const float* reg_w2      = (const float*)d_in[11];
    const float* reg_b2      = (const float*)d_in[12];
    const float* init_conv_w = (const float*)d_in[13];
    const float* init_conv_b = (const float*)d_in[14];
    const float* init_out_w  = (const float*)d_in[15];
    const float* init_out_b  = (const float*)d_in[16];
    const float* dcn_cls_w   = (const float*)d_in[17];
    const float* cls_out_w   = (const float*)d_in[18];
    const float* cls_out_b   = (const float*)d_in[19];
    const float* dcn_ref_w   = (const float*)d_in[20];
    const float* ref_out_w   = (const float*)d_in[21];
    const float* ref_out_b   = (const float*)d_in[22];

    float* out = (float*)d_out;

    char* ws = (char*)d_ws;
    const size_t IMG = (size_t)Bn * HWn * Cn * sizeof(unsigned short);  // 16 MiB
    unsigned short* B0 = (unsigned short*)ws; ws += IMG;
    unsigned short* B1 = (unsigned short*)ws; ws += IMG;
    unsigned short* B2 = (unsigned short*)ws; ws += IMG;
    unsigned short* B3 = (unsigned short*)ws; ws += IMG;
    float* O27 = (float*)ws; ws += (size_t)Bn * 27 * HWn * sizeof(float);
    const size_t WSZ = (size_t)9 * Cn * Cn;   // 589824 elems per weight
    unsigned short* Wpk = (unsigned short*)ws; ws += 9 * WSZ * sizeof(unsigned short);
    unsigned short* WhAll = (unsigned short*)ws; ws += 160 * Cn * sizeof(unsigned short);
    unsigned short* ZB = (unsigned short*)ws;  ws += 1024;

    unsigned short* W_cls0 = Wpk + 0 * WSZ;
    unsigned short* W_cls1 = Wpk + 1 * WSZ;
    unsigned short* W_cls2 = Wpk + 2 * WSZ;
    unsigned short* W_reg0 = Wpk + 3 * WSZ;
    unsigned short* W_reg1 = Wpk + 4 * WSZ;
    unsigned short* W_reg2 = Wpk + 5 * WSZ;
    unsigned short* W_init = Wpk + 6 * WSZ;
    unsigned short* W_dcls = Wpk + 7 * WSZ;
    unsigned short* W_dref = Wpk + 8 * WSZ;
    unsigned short* Wh27 = WhAll;
    unsigned short* Wh80 = WhAll + 32 * Cn;
    unsigned short* Wh18 = WhAll + 128 * Cn;

    const dim3 blk(256);
    const dim3 blk5(512);
    const dim3 xgrd(512, 8, Bn);

    WPtrs wp;
    wp.p[0] = cls_w0; wp.p[1] = cls_w1; wp.p[2] = cls_w2;
    wp.p[3] = reg_w0; wp.p[4] = reg_w1; wp.p[5] = reg_w2;
    wp.p[6] = init_conv_w; wp.p[7] = dcn_cls_w; wp.p[8] = dcn_ref_w;
    repackAll<<<2304, blk, 0, stream>>>(wp, Wpk, ZB);
    HPtrs hp; hp.w[0] = init_out_w; hp.w[1] = cls_out_w; hp.w[2] = ref_out_w;
    repackHeads<<<160, blk, 0, stream>>>(hp, WhAll);
    xinK<<<xgrd, blk, 0, stream>>>(x, B0);

    CJobs j;
    // L0 (shared input)
    j.feat[0] = B0; j.W[0] = W_cls0; j.bias[0] = cls_b0; j.out[0] = B1;
    j.feat[1] = B0; j.W[1] = W_reg0; j.bias[1] = reg_b0; j.out[1] = B2;
    convGemm256<<<dim3(128, 1, 2), blk5, 0, stream>>>(j, ZB);
    // L1
    j.feat[0] = B1; j.W[0] = W_cls1; j.bias[0] = cls_b1; j.out[0] = B3;
    j.feat[1] = B2; j.W[1] = W_reg1; j.bias[1] = reg_b1; j.out[1] = B0;
    convGemm256<<<dim3(128, 1, 2), blk5, 0, stream>>>(j, ZB);
    // L2
    j.feat[0] = B3; j.W[0] = W_cls2; j.bias[0] = cls_b2; j.out[0] = B1;   // CLS
    j.feat[1] = B0; j.W[1] = W_reg2; j.bias[1] = reg_b2; j.out[1] = B2;   // PTS
    convGemm256<<<dim3(128, 1, 2), blk5, 0, stream>>>(j, ZB);
    // init conv
    convGemm<<<dim3(256, 2, 1), blk, 0, stream>>>(B2, W_init, init_conv_b, ZB, B3);
    headGemm<27, 32, false, false><<<256, blk, 0, stream>>>(B3, Wh27, init_out_b, O27, nullptr, 0, nullptr);
    // both DCNs in one launch (64px strips, 2 blocks/CU)
    DJobs dj;
    dj.feat[0] = B1; dj.W[0] = W_dcls; dj.out[0] = B0; dj.mask[0] = 1;
    dj.feat[1] = B2; dj.W[1] = W_dref; dj.out[1] = B3; dj.mask[1] = 0;
    dcnGemm<<<1024, blk5, 0, stream>>>(dj, O27);
    // heads
    headGemm<80, 96, false, false><<<256, blk, 0, stream>>>(B0, Wh80, cls_out_b, out, nullptr, 0, nullptr);
    headGemm<18, 32, true, true><<<256, blk, 0, stream>>>(
        B3, Wh18, ref_out_b,
        out + (size_t)Bn * NCn * HWn,          // wh
        O27, 27,
        out + (size_t)Bn * NCn * HWn + (size_t)Bn * 2 * HWn);  // reg
}

// Round 9
// 567.786 us; speedup vs baseline: 1.2146x; 1.2146x over previous
//
#include <hip/hip_runtime.h>

#define Bn 2
#define Cn 256
#define Hn 128
#define Wn 128
#define HWn 16384
#define NCn 80

typedef __attribute__((ext_vector_type(4))) float f32x4;
typedef __attribute__((ext_vector_type(8))) short bf16x8;

__device__ __forceinline__ float blo(unsigned u) {
    union { unsigned u; float f; } x; x.u = u << 16; return x.f;
}
__device__ __forceinline__ float braw(unsigned u) {   // high bf16 + low-mantissa noise (<=1ulp-ish)
    union { unsigned u; float f; } x; x.u = u; return x.f;
}
__device__ __forceinline__ unsigned short f2bf(float f) {
    union { float f; unsigned u; } x; x.f = f;
    unsigned u = x.u + 0x7fffu + ((x.u >> 16) & 1u);   // RNE
    return (unsigned short)(u >> 16);
}
__device__ __forceinline__ unsigned pk2bf(float e0, float e1) {
    unsigned r;
    asm("v_cvt_pk_bf16_f32 %0, %1, %2" : "=v"(r) : "v"(e0), "v"(e1));
    return r;
}

// async global->LDS, 16B per lane, wave-uniform LDS base + lane*16
#define GLOAD16(gp, lp) __builtin_amdgcn_global_load_lds( \
    (__attribute__((address_space(1))) unsigned int*)(gp), \
    (__attribute__((address_space(3))) unsigned int*)(lp), 16, 0, 0)

// ---------- x (NCHW f32) -> NHWC bf16 ----------
__global__ __launch_bounds__(256) void xinK(const float* __restrict__ x,
                                            unsigned short* __restrict__ o) {
    __shared__ float tb[32][33];
    const int b = blockIdx.z;
    const int hw0 = blockIdx.x * 32, c0 = blockIdx.y * 32;
    const int tx = threadIdx.x & 31, ty = threadIdx.x >> 5;
    const float* ip = x + ((size_t)(b * Cn + c0)) * HWn + hw0;
#pragma unroll
    for (int r = 0; r < 4; ++r) tb[ty + 8 * r][tx] = ip[(size_t)(ty + 8 * r) * HWn + tx];
    __syncthreads();
    unsigned short* op = o + ((size_t)(b * HWn + hw0)) * Cn + c0;
#pragma unroll
    for (int r = 0; r < 4; ++r) op[(size_t)(ty + 8 * r) * Cn + tx] = f2bf(tb[tx][ty + 8 * r]);
}

// ---------- fused repack: 9x conv weights + 3 head weights + ZB zero ----------
struct RPtrs { const float* w3[9]; const float* wh[3]; };
__global__ __launch_bounds__(256) void repackAllK(RPtrs rp,
                                                  unsigned short* __restrict__ dst3,
                                                  unsigned short* __restrict__ dstH,
                                                  unsigned short* __restrict__ zb) {
    if (blockIdx.x < 2304) {
        if (blockIdx.x == 0) { zb[threadIdx.x] = 0; zb[256 + threadIdx.x] = 0; }
        const int t = blockIdx.x * 256 + threadIdx.x;     // < 589824
        const int widx = t >> 16;                          // 0..8
        const int r = t & 65535;                           // oc*256+ic
        const float* s = rp.w3[widx] + (size_t)r * 9;
        float v[9];
#pragma unroll
        for (int k = 0; k < 9; ++k) v[k] = s[k];
        unsigned short* d = dst3 + (size_t)widx * 589824 + r;
#pragma unroll
        for (int k = 0; k < 9; ++k) d[(size_t)k * 65536] = f2bf(v[k]);
    } else {
        const int t = (blockIdx.x - 2304) * 256 + threadIdx.x;   // < 160*256
        const int ic = t & 255, row = t >> 8;
        int which, oc, OC;
        if (row < 32)       { which = 0; oc = row;       OC = 27; }
        else if (row < 128) { which = 1; oc = row - 32;  OC = 80; }
        else                { which = 2; oc = row - 128; OC = 18; }
        dstH[t] = (oc < OC) ? f2bf(rp.wh[which][(size_t)oc * Cn + ic]) : (unsigned short)0;
    }
}

// ---------- batched implicit-GEMM 3x3 conv (128^2 tile, proven 97us dual) ----------
// grid (256, 2, NJ), block 256 (4 waves, 2 oc x 2 px), tile 128oc x 128px, BK=64
struct CJobs {
    const unsigned short* feat[2];
    const unsigned short* W[2];
    const float* bias[2];
    unsigned short* out[2];
};
__global__ __launch_bounds__(256, 2) void convGemm(CJobs jobs,
                                                   const unsigned short* __restrict__ zb) {
    const int jz = blockIdx.z;
    const unsigned short* feat = jobs.feat[jz];
    const unsigned short* Wp = jobs.W[jz];
    const float* bias = jobs.bias[jz];
    unsigned short* outp = jobs.out[jz];

    __shared__ __align__(16) unsigned short lA[2][8192];   // weights [oc][ic]
    __shared__ __align__(16) unsigned short lB[2][8192];   // feat [px][ic]
    const int tid = threadIdx.x;
    const int l = tid & 63, w = tid >> 6;
    const int w_oc = w & 1, w_px = w >> 1;
    const int ry = (blockIdx.x & 7) * 32 + (blockIdx.x >> 3);   // XCD-chunked rows
    const int b = ry >> 7, y = ry & 127;
    const int oc0 = blockIdx.y * 128;
    const int lr = l & 15, lg = l >> 4;

    int rI[4], cI[4], dI[4];
#pragma unroll
    for (int i = 0; i < 4; ++i) {
        int ps = (i * 4 + w) * 64 + l;            // physical 16B slot
        rI[i] = ps >> 3;
        cI[i] = ((ps & 7) ^ (rI[i] & 7)) * 8;     // pre-swizzled source chunk
        dI[i] = (i * 4 + w) * 512;                // wave-uniform LDS elem base
    }

    f32x4 acc[4][4];
#pragma unroll
    for (int i = 0; i < 4; ++i)
#pragma unroll
        for (int j = 0; j < 4; ++j) acc[i][j] = (f32x4){0.f, 0.f, 0.f, 0.f};

    auto stage = [&](int p, int bufIdx) {
        const int k = p >> 2, c0 = (p & 3) * 64;
        const int dy = k / 3 - 1, dx = k % 3 - 1;
        const int yy = y + dy;
        const bool vy = (unsigned)yy < (unsigned)Hn;
        const size_t fbase = ((size_t)(b * Hn + yy)) * Wn;
        const unsigned short* wk = Wp + (size_t)k * 65536 + (size_t)oc0 * Cn + c0;
        unsigned short* la = lA[bufIdx];
        unsigned short* lb = lB[bufIdx];
#pragma unroll
        for (int i = 0; i < 4; ++i)
            GLOAD16(wk + rI[i] * Cn + cI[i], la + dI[i]);
#pragma unroll
        for (int i = 0; i < 4; ++i) {
            const int pxs = rI[i] + dx;
            const unsigned short* g = (vy && (unsigned)pxs < (unsigned)Wn)
                ? feat + ((fbase + pxs) * Cn + c0 + cI[i])
                : zb;
            GLOAD16(g, lb + dI[i]);
        }
    };

    stage(0, 0);
    __syncthreads();

#pragma unroll 1
    for (int p = 0; p < 36; ++p) {
        const int cur = p & 1;
        if (p < 35) stage(p + 1, cur ^ 1);      // async, overlaps MFMA below
        const unsigned short* la = lA[cur];
        const unsigned short* lb = lB[cur];
#pragma unroll
        for (int h = 0; h < 2; ++h) {
            const int ch = h * 4 + lg;
            bf16x8 av[4], bv[4];
#pragma unroll
            for (int fm = 0; fm < 4; ++fm) {
                const int row = w_oc * 64 + fm * 16 + lr;
                av[fm] = *(const bf16x8*)&la[row * 64 + ((ch ^ (row & 7)) * 8)];
            }
#pragma unroll
            for (int fn = 0; fn < 4; ++fn) {
                const int row = w_px * 64 + fn * 16 + lr;
                bv[fn] = *(const bf16x8*)&lb[row * 64 + ((ch ^ (row & 7)) * 8)];
            }
#pragma unroll
            for (int fm = 0; fm < 4; ++fm)
#pragma unroll
                for (int fn = 0; fn < 4; ++fn)
                    acc[fm][fn] = __builtin_amdgcn_mfma_f32_16x16x32_bf16(
                        av[fm], bv[fn], acc[fm][fn], 0, 0, 0);
        }
        __syncthreads();
    }

#pragma unroll
    for (int fm = 0; fm < 4; ++fm) {
        const int ocb = oc0 + w_oc * 64 + fm * 16 + lg * 4;
        const float b0 = bias[ocb], b1 = bias[ocb + 1], b2 = bias[ocb + 2], b3 = bias[ocb + 3];
#pragma unroll
        for (int fn = 0; fn < 4; ++fn) {
            const int px = w_px * 64 + fn * 16 + lr;
            f32x4 v = acc[fm][fn];
            uint2 st;
            st.x = pk2bf(fmaxf(v[0] + b0, 0.f), fmaxf(v[1] + b1, 0.f));
            st.y = pk2bf(fmaxf(v[2] + b2, 0.f), fmaxf(v[3] + b3, 0.f));
            *(uint2*)&outp[((size_t)ry * Wn + px) * Cn + ocb] = st;
        }
    }
}

// ---------- deformable conv: 256oc x 64px sampled implicit GEMM, dual-job fused ----------
// grid (1024), block 512 (8 waves, 4 oc x 2 px), BK=64, (fm,fn)=(4,2), 80 KB LDS,
// 2 blocks/CU. Corners issued BEFORE stageA (corner-wait = vmcnt(4)); interp+ds_write
// after MFMA (T14); offset scalars for k+1 prefetched 2 phases early (3 VGPRs);
// interp packing via v_cvt_pk_bf16_f32 + braw (validated r8).
struct DJobs {
    const unsigned short* feat[2];
    const unsigned short* W[2];
    unsigned short* out[2];
    int mask[2];
};
__global__ __launch_bounds__(512, 4) void dcnGemm(DJobs jobs,
                                                  const float* __restrict__ o27) {
    const int jz = blockIdx.x >> 9;
    const unsigned short* feat = jobs.feat[jz];
    const unsigned short* Wp = jobs.W[jz];
    unsigned short* outp = jobs.out[jz];
    const bool HASMASK = jobs.mask[jz] != 0;

    __shared__ __align__(16) unsigned short lA[2][16384];   // 256oc x 64ch
    __shared__ __align__(16) unsigned short lB[2][4096];    // 64px x 64ch
    const int tid = threadIdx.x;
    const int l = tid & 63, w = tid >> 6;
    const int w_oc = w & 3, w_px = w >> 2;
    const int lb_ = blockIdx.x & 511;
    const int g = (lb_ & 7) * 64 + (lb_ >> 3);  // XCD-chunked
    const int ry = g >> 1, st = g & 1;
    const int b = ry >> 7, y = ry & 127;
    const int x0 = st * 64;
    const int lr = l & 15, lg = l >> 4;

    int rIA[4], cIA[4], dIA[4];
#pragma unroll
    for (int i = 0; i < 4; ++i) {
        int ps = (i * 8 + w) * 64 + l;
        rIA[i] = ps >> 3;
        cIA[i] = ((ps & 7) ^ (rIA[i] & 7)) * 8;
        dIA[i] = (i * 8 + w) * 512;
    }

    const int sp = tid >> 3;          // sampled px 0..63
    const int pc = tid & 7;           // chunk 0..7
    const int xg = x0 + sp;
    const int wslot = sp * 64 + ((pc ^ (sp & 7)) * 8);

    const float* ob = o27 + (size_t)b * 27 * HWn + y * Wn + xg;
    const unsigned short* fb = feat + (size_t)b * HWn * Cn;

    f32x4 acc[4][2];
#pragma unroll
    for (int i = 0; i < 4; ++i)
#pragma unroll
        for (int j = 0; j < 2; ++j) acc[i][j] = (f32x4){0.f, 0.f, 0.f, 0.f};

    int ci0, ci1, ci2, ci3;
    float cw0, cw1, cw2, cw3;
    float pofy, pofx, pom;             // offset prefetch (3 VGPRs)

    auto sampFromRegs = [&](int k) {   // consume pofy/pofx/pom -> ci/cw
        const float py = (float)(y + k / 3 - 1) + pofy;
        const float px = (float)(xg + k % 3 - 1) + pofx;
        const float y0f = floorf(py), x0f = floorf(px);
        const float wy1 = py - y0f, wx1 = px - x0f;
        const int iy0 = (int)y0f, ix0 = (int)x0f;
        const int iy1 = iy0 + 1, ix1 = ix0 + 1;
        const bool vy0 = (unsigned)iy0 < (unsigned)Hn, vy1 = (unsigned)iy1 < (unsigned)Hn;
        const bool vx0 = (unsigned)ix0 < (unsigned)Wn, vx1 = (unsigned)ix1 < (unsigned)Wn;
        const int yc0 = min(max(iy0, 0), Hn - 1), yc1 = min(max(iy1, 0), Hn - 1);
        const int xc0 = min(max(ix0, 0), Wn - 1), xc1 = min(max(ix1, 0), Wn - 1);
        cw0 = (vy0 && vx0) ? (1.f - wy1) * (1.f - wx1) * pom : 0.f;
        cw1 = (vy0 && vx1) ? (1.f - wy1) * wx1 * pom : 0.f;
        cw2 = (vy1 && vx0) ? wy1 * (1.f - wx1) * pom : 0.f;
        cw3 = (vy1 && vx1) ? wy1 * wx1 * pom : 0.f;
        ci0 = (yc0 * Wn + xc0) * Cn;
        ci1 = (yc0 * Wn + xc1) * Cn;
        ci2 = (yc1 * Wn + xc0) * Cn;
        ci3 = (yc1 * Wn + xc1) * Cn;
    };
    auto prefOff = [&](int k) {
        pofy = ob[(size_t)(2 * k) * HWn];
        pofx = ob[(size_t)(2 * k + 1) * HWn];
        pom = HASMASK ? ob[(size_t)(18 + k) * HWn] : 1.f;
    };

    int4 q0, q1, q2, q3;
    auto cornerLoads = [&](int p) {
        const int cb = (p & 3) * 64 + pc * 8;
        q0 = *(const int4*)(fb + ci0 + cb);
        q1 = *(const int4*)(fb + ci1 + cb);
        q2 = *(const int4*)(fb + ci2 + cb);
        q3 = *(const int4*)(fb + ci3 + cb);
    };
    auto stageA = [&](int p, int bufIdx) {
        const int k = p >> 2, c0 = (p & 3) * 64;
        const unsigned short* wk = Wp + (size_t)k * 65536 + c0;
        unsigned short* la = lA[bufIdx];
#pragma unroll
        for (int i = 0; i < 4; ++i)
            GLOAD16(wk + rIA[i] * Cn + cIA[i], la + dIA[i]);
    };
    auto interpWrite = [&](int bufIdx) {
        unsigned uu[4];
#pragma unroll
        for (int jj = 0; jj < 4; ++jj) {
            const unsigned a0 = ((const unsigned*)&q0)[jj];
            const unsigned a1 = ((const unsigned*)&q1)[jj];
            const unsigned a2 = ((const unsigned*)&q2)[jj];
            const unsigned a3 = ((const unsigned*)&q3)[jj];
            float e0 = cw0 * blo(a0) + cw1 * blo(a1) + cw2 * blo(a2) + cw3 * blo(a3);
            float e1 = cw0 * braw(a0) + cw1 * braw(a1) + cw2 * braw(a2) + cw3 * braw(a3);
            uu[jj] = pk2bf(e0, e1);
        }
        int4 pk; pk.x = uu[0]; pk.y = uu[1]; pk.z = uu[2]; pk.w = uu[3];
        *(int4*)&lB[bufIdx][wslot] = pk;
    };

    // prologue (k=0)
    prefOff(0);
    sampFromRegs(0);
    cornerLoads(0);
    stageA(0, 0);
    interpWrite(0);
    prefOff(1);        // offsets for k=1, consumed at p=3
    __syncthreads();

#pragma unroll 1
    for (int p = 0; p < 36; ++p) {
        const int cur = p & 1;
        if (p < 35) {
            if (((p + 1) & 3) == 0) sampFromRegs((p + 1) >> 2);   // regs only, no mem latency
            cornerLoads(p + 1);           // issued FIRST (older in vmcnt order)
            stageA(p + 1, cur ^ 1);       // stays in flight past corner-wait
            if ((p & 3) == 1 && (p >> 2) < 8) prefOff((p >> 2) + 2);  // k+2? no: next-next guard
        }
        const unsigned short* la = lA[cur];
        const unsigned short* lb = lB[cur];
#pragma unroll
        for (int h = 0; h < 2; ++h) {
            const int ch = h * 4 + lg;
            bf16x8 av[4], bv[2];
#pragma unroll
            for (int fm = 0; fm < 4; ++fm) {
                const int row = w_oc * 64 + fm * 16 + lr;
                av[fm] = *(const bf16x8*)&la[row * 64 + ((ch ^ (row & 7)) * 8)];
            }
#pragma unroll
            for (int fn = 0; fn < 2; ++fn) {
                const int row = w_px * 32 + fn * 16 + lr;
                bv[fn] = *(const bf16x8*)&lb[row * 64 + ((ch ^ (row & 7)) * 8)];
            }
#pragma unroll
            for (int fm = 0; fm < 4; ++fm)
#pragma unroll
                for (int fn = 0; fn < 2; ++fn)
                    acc[fm][fn] = __builtin_amdgcn_mfma_f32_16x16x32_bf16(
                        av[fm], bv[fn], acc[fm][fn], 0, 0, 0);
        }
        if (p < 35) interpWrite(cur ^ 1);   // corner-wait + interp AFTER MFMA
        __syncthreads();
    }

#pragma unroll
    for (int fm = 0; fm < 4; ++fm) {
        const int oc = w_oc * 64 + fm * 16 + lg * 4;
#pragma unroll
        for (int fn = 0; fn < 2; ++fn) {
            const int px = x0 + w_px * 32 + fn * 16 + lr;
            f32x4 v = acc[fm][fn];
            uint2 stv;
            stv.x = pk2bf(fmaxf(v[0], 0.f), fmaxf(v[1], 0.f));
            stv.y = pk2bf(fmaxf(v[2], 0.f), fmaxf(v[3], 0.f));
            *(uint2*)&outp[((size_t)ry * Wn + px) * Cn + oc] = stv;
        }
    }
}

// NOTE on prefOff timing: offsets for k+1 are loaded at the phase where
// (p&3)==1 of k-1... simpler invariant used above: prefOff(k+1) must complete
// before phase 4k+3. Prologue does prefOff(1); the in-loop call at (p&3)==1
// loads (p>>2)+2 which at p=4m+1 is k=m+2, consumed at p=4(m+1)+3 — 6 phases
// later. Guard (p>>2)<8 keeps k<=9... k max consumed is 8 (sampFromRegs(8) at
// p=31). prefOff(9) would read OOB offsets: guarded by (p>>2)<8 → max k loaded
// = 9? (p>>2)+2 <= 9 when p>>2 == 7. Hmm: sampFromRegs only consumes k<=8, and
// prefOff(9) at p>>2==7 reads ob[(18)*HWn.. or (2*9)*HWn] = channel 18 — still
// within the 27-channel O27 buffer, harmless and unused.

// ---------- MFMA 1x1 head body (shared by head27 / tail kernel) ----------
template <int OC, int PM, bool ADD, bool POST>
__device__ __forceinline__ void headBody(int bx,
                                         const unsigned short* __restrict__ feat,
                                         const unsigned short* __restrict__ Wp,
                                         const float* __restrict__ bias,
                                         float* __restrict__ out,
                                         const float* __restrict__ add, int addC,
                                         float* __restrict__ reg,
                                         unsigned short* lA, unsigned short* lB,
                                         float (*lR)[128]) {
    constexpr int MF = PM / 16;
    constexpr int NA = PM * 8 / 256;
    const int tid = threadIdx.x;
    const int l = tid & 63, w = tid >> 6;
    const int ry = (bx & 7) * 32 + (bx >> 3);
    const int b = ry >> 7, y = ry & 127;
    const int lr = l & 15, lg = l >> 4;

    int rIA[NA], cIA[NA], dIA[NA];
#pragma unroll
    for (int i = 0; i < NA; ++i) {
        int ps = (i * 4 + w) * 64 + l;
        rIA[i] = ps >> 3;
        cIA[i] = ((ps & 7) ^ (rIA[i] & 7)) * 8;
        dIA[i] = (i * 4 + w) * 512;
    }
    int rIB[4], cIB[4], dIB[4];
#pragma unroll
    for (int i = 0; i < 4; ++i) {
        int ps = (i * 4 + w) * 64 + l;
        rIB[i] = ps >> 3;
        cIB[i] = ((ps & 7) ^ (rIB[i] & 7)) * 8;
        dIB[i] = (i * 4 + w) * 512;
    }

    f32x4 acc[MF][2];
#pragma unroll
    for (int i = 0; i < MF; ++i)
#pragma unroll
        for (int j = 0; j < 2; ++j) acc[i][j] = (f32x4){0.f, 0.f, 0.f, 0.f};

    const unsigned short* frow = feat + ((size_t)ry * Wn) * Cn;

#pragma unroll 1
    for (int cc = 0; cc < 4; ++cc) {
        const int c0 = cc * 64;
#pragma unroll
        for (int i = 0; i < NA; ++i)
            GLOAD16(Wp + (size_t)rIA[i] * Cn + c0 + cIA[i], &lA[dIA[i]]);
#pragma unroll
        for (int i = 0; i < 4; ++i)
            GLOAD16(frow + (size_t)rIB[i] * Cn + c0 + cIB[i], &lB[dIB[i]]);
        __syncthreads();
#pragma unroll
        for (int h = 0; h < 2; ++h) {
            const int ch = h * 4 + lg;
            bf16x8 av[MF], bv[2];
#pragma unroll
            for (int fm = 0; fm < MF; ++fm) {
                const int row = fm * 16 + lr;
                av[fm] = *(const bf16x8*)&lA[row * 64 + ((ch ^ (row & 7)) * 8)];
            }
#pragma unroll
            for (int fn = 0; fn < 2; ++fn) {
                const int row = w * 32 + fn * 16 + lr;
                bv[fn] = *(const bf16x8*)&lB[row * 64 + ((ch ^ (row & 7)) * 8)];
            }
#pragma unroll
            for (int fm = 0; fm < MF; ++fm)
#pragma unroll
                for (int fn = 0; fn < 2; ++fn)
                    acc[fm][fn] = __builtin_amdgcn_mfma_f32_16x16x32_bf16(
                        av[fm], bv[fn], acc[fm][fn], 0, 0, 0);
        }
        __syncthreads();
    }

    if (!POST) {
#pragma unroll
        for (int fm = 0; fm < MF; ++fm) {
            const int ocb = fm * 16 + lg * 4;
            if (ocb >= OC) break;
#pragma unroll
            for (int j = 0; j < 4; ++j) {
                const int oc = ocb + j;
                if (oc >= OC) break;
                const float bs = bias[oc];
#pragma unroll
                for (int fn = 0; fn < 2; ++fn) {
                    const int px = w * 32 + fn * 16 + lr;
                    float r = acc[fm][fn][j] + bs;
                    if (ADD) r += add[((size_t)(b * addC + oc)) * HWn + y * Wn + px];
                    out[((size_t)(b * OC + oc)) * HWn + y * Wn + px] = r;
                }
            }
        }
    } else {
#pragma unroll
        for (int fm = 0; fm < MF; ++fm) {
            const int ocb = fm * 16 + lg * 4;
#pragma unroll
            for (int j = 0; j < 4; ++j) {
                const int oc = ocb + j;
                if (oc < 18) {
                    const float bs = bias[oc];
#pragma unroll
                    for (int fn = 0; fn < 2; ++fn) {
                        const int px = w * 32 + fn * 16 + lr;
                        float r = acc[fm][fn][j] + bs
                                + add[((size_t)(b * addC + oc)) * HWn + y * Wn + px];
                        lR[oc][px] = r;
                    }
                }
            }
        }
        __syncthreads();
        if (tid < 128) {
            const int px = tid;
            float v[18];
#pragma unroll
            for (int c = 0; c < 18; ++c) v[c] = lR[c][px];
            float s0 = 0.f, s1 = 0.f;
#pragma unroll
            for (int q = 0; q < 9; ++q) { s0 += v[2 * q]; s1 += v[2 * q + 1]; }
            float m0 = s0 * (1.f / 9.f), m1 = s1 * (1.f / 9.f);
            float w0 = 0.f, w1 = 0.f;
#pragma unroll
            for (int q = 0; q < 9; ++q) {
                w0 = fmaxf(w0, fabsf(v[2 * q] + m0));
                w1 = fmaxf(w1, fabsf(v[2 * q + 1] + m1));
            }
            const size_t hw = (size_t)y * Wn + px;
            out[(size_t)(b * 2 + 0) * HWn + hw] = w0;
            out[(size_t)(b * 2 + 1) * HWn + hw] = w1;
            reg[(size_t)(b * 2 + 0) * HWn + hw] = m0;
            reg[(size_t)(b * 2 + 1) * HWn + hw] = m1;
        }
    }
}

// ---------- head27 (init offsets) ----------
__global__ __launch_bounds__(256, 2) void head27K(const unsigned short* __restrict__ feat,
                                                  const unsigned short* __restrict__ Wp,
                                                  const float* __restrict__ bias,
                                                  float* __restrict__ out) {
    __shared__ __align__(16) unsigned short sA[32 * 64];
    __shared__ __align__(16) unsigned short sB[128 * 64];
    headBody<27, 32, false, false>(blockIdx.x, feat, Wp, bias, out,
                                   nullptr, 0, nullptr, sA, sB, nullptr);
}

// ---------- fused tail: head80 (blocks 0..255) + head18+post (blocks 256..511) ----------
__global__ __launch_bounds__(256, 2) void headTailK(const unsigned short* __restrict__ f80,
                                                    const unsigned short* __restrict__ W80,
                                                    const float* __restrict__ b80,
                                                    float* __restrict__ out80,
                                                    const unsigned short* __restrict__ f18,
                                                    const unsigned short* __restrict__ W18,
                                                    const float* __restrict__ b18,
                                                    const float* __restrict__ add27,
                                                    float* __restrict__ wh,
                                                    float* __restrict__ reg) {
    __shared__ __align__(16) unsigned short sA[96 * 64];
    __shared__ __align__(16) unsigned short sB[128 * 64];
    __shared__ float sR[18][128];
    if (blockIdx.x < 256) {
        headBody<80, 96, false, false>(blockIdx.x, f80, W80, b80, out80,
                                       nullptr, 0, nullptr, sA, sB, nullptr);
    } else {
        headBody<18, 32, true, true>(blockIdx.x - 256, f18, W18, b18, wh,
                                     add27, 27, reg, sA, sB, sR);
    }
}

// ---------- host ----------
extern "C" void kernel_launch(void* const* d_in, const int* in_sizes, int n_in,
                              void* d_out, int out_size, void* d_ws, size_t ws_size,
                              hipStream_t stream) {
    const float* x           = (const float*)d_in[0];
    const float* cls_w0      = (const float*)d_in[1];
    const float* cls_b0      = (const float*)d_in[2];
    const float* reg_w0      = (const float*)d_in[3];
    const float* reg_b0      = (const float*)d_in[4];
    const float* cls_w1      = (const float*)d_in[5];
    const float* cls_b1      = (const float*)d_in[6];
    const float* reg_w1      = (const float*)d_in[7];
    const float* reg_b1      = (const float*)d_in[8];
    const float* cls_w2      = (const float*)d_in[9];
    const float* cls_b2      = (const float*)d_in[10];
    const float* reg_w2      = (const float*)d_in[11];
    const float* reg_b2      = (const float*)d_in[12];
    const float* init_conv_w = (const float*)d_in[13];
    const float* init_conv_b = (const float*)d_in[14];
    const float* init_out_w  = (const float*)d_in[15];
    const float* init_out_b  = (const float*)d_in[16];
    const float* dcn_cls_w   = (const float*)d_in[17];
    const float* cls_out_w   = (const float*)d_in[18];
    const float* cls_out_b   = (const float*)d_in[19];
    const float* dcn_ref_w   = (const float*)d_in[20];
    const float* ref_out_w   = (const float*)d_in[21];
    const float* ref_out_b   = (const float*)d_in[22];

    float* out = (float*)d_out;

    char* ws = (char*)d_ws;
    const size_t IMG = (size_t)Bn * HWn * Cn * sizeof(unsigned short);  // 16 MiB
    unsigned short* B0 = (unsigned short*)ws; ws += IMG;
    unsigned short* B1 = (unsigned short*)ws; ws += IMG;
    unsigned short* B2 = (unsigned short*)ws; ws += IMG;
    unsigned short* B3 = (unsigned short*)ws; ws += IMG;
    float* O27 = (float*)ws; ws += (size_t)Bn * 27 * HWn * sizeof(float);
    const size_t WSZ = (size_t)9 * Cn * Cn;   // 589824 elems per weight
    unsigned short* Wpk = (unsigned short*)ws; ws += 9 * WSZ * sizeof(unsigned short);
    unsigned short* WhAll = (unsigned short*)ws; ws += 160 * Cn * sizeof(unsigned short);
    unsigned short* ZB = (unsigned short*)ws;  ws += 1024;

    unsigned short* W_cls0 = Wpk + 0 * WSZ;
    unsigned short* W_cls1 = Wpk + 1 * WSZ;
    unsigned short* W_cls2 = Wpk + 2 * WSZ;
    unsigned short* W_reg0 = Wpk + 3 * WSZ;
    unsigned short* W_reg1 = Wpk + 4 * WSZ;
    unsigned short* W_reg2 = Wpk + 5 * WSZ;
    unsigned short* W_init = Wpk + 6 * WSZ;
    unsigned short* W_dcls = Wpk + 7 * WSZ;
    unsigned short* W_dref = Wpk + 8 * WSZ;
    unsigned short* Wh27 = WhAll;
    unsigned short* Wh80 = WhAll + 32 * Cn;
    unsigned short* Wh18 = WhAll + 128 * Cn;

    const dim3 blk(256);
    const dim3 xgrd(512, 8, Bn);

    RPtrs rp;
    rp.w3[0] = cls_w0; rp.w3[1] = cls_w1; rp.w3[2] = cls_w2;
    rp.w3[3] = reg_w0; rp.w3[4] = reg_w1; rp.w3[5] = reg_w2;
    rp.w3[6] = init_conv_w; rp.w3[7] = dcn_cls_w; rp.w3[8] = dcn_ref_w;
    rp.wh[0] = init_out_w; rp.wh[1] = cls_out_w; rp.wh[2] = ref_out_w;
    repackAllK<<<2464, blk, 0, stream>>>(rp, Wpk, WhAll, ZB);
    xinK<<<xgrd, blk, 0, stream>>>(x, B0);

    CJobs j;
    // L0 (shared input)
    j.feat[0] = B0; j.W[0] = W_cls0; j.bias[0] = cls_b0; j.out[0] = B1;
    j.feat[1] = B0; j.W[1] = W_reg0; j.bias[1] = reg_b0; j.out[1] = B2;
    convGemm<<<dim3(256, 2, 2), blk, 0, stream>>>(j, ZB);
    // L1
    j.feat[0] = B1; j.W[0] = W_cls1; j.bias[0] = cls_b1; j.out[0] = B3;
    j.feat[1] = B2; j.W[1] = W_reg1; j.bias[1] = reg_b1; j.out[1] = B0;
    convGemm<<<dim3(256, 2, 2), blk, 0, stream>>>(j, ZB);
    // L2
    j.feat[0] = B3; j.W[0] = W_cls2; j.bias[0] = cls_b2; j.out[0] = B1;   // CLS
    j.feat[1] = B0; j.W[1] = W_reg2; j.bias[1] = reg_b2; j.out[1] = B2;   // PTS
    convGemm<<<dim3(256, 2, 2), blk, 0, stream>>>(j, ZB);
    // init conv (single job via grid.z=1)
    j.feat[0] = B2; j.W[0] = W_init; j.bias[0] = init_conv_b; j.out[0] = B3;
    convGemm<<<dim3(256, 2, 1), blk, 0, stream>>>(j, ZB);
    head27K<<<256, blk, 0, stream>>>(B3, Wh27, init_out_b, O27);
    // both DCNs in one launch
    DJobs dj;
    dj.feat[0] = B1; dj.W[0] = W_dcls; dj.out[0] = B0; dj.mask[0] = 1;
    dj.feat[1] = B2; dj.W[1] = W_dref; dj.out[1] = B3; dj.mask[1] = 0;
    dcnGemm<<<1024, dim3(512), 0, stream>>>(dj, O27);
    // fused tail heads
    headTailK<<<512, blk, 0, stream>>>(
        B0, Wh80, cls_out_b, out,
        B3, Wh18, ref_out_b, O27,
        out + (size_t)Bn * NCn * HWn,                                   // wh
        out + (size_t)Bn * NCn * HWn + (size_t)Bn * 2 * HWn);           // reg
}